// Round 12
// baseline (257.855 us; speedup 1.0000x reference)
//
#include <hip/hip_runtime.h>

// GraphTransformerLayer — MI355X
// r6=574 ... r20=258.4 r25=294(regression) r26=259.8 r27=251.4 (BEST: tail
// merge; tail_kernel 44.2us visible: 313 blocks ~1.2/CU, occupancy 9.7%,
// ~19 barrier-separated stage->drain->compute rounds, zero DMA/compute
// overlap — serial critical path IS the kernel).
// r28: tail W-staging DOUBLE-BUFFERED (wsA=F1-role, wsB=F2-role, fixed roles
//      -> no runtime buffer idx). stage(next) issued BEFORE current MFMA
//      phase; barrier drains DMA that had a full compute phase to land.
//      Barriers 19->11. LDS 80KB -> 2 blk/CU (grid 1.2/CU, harmless).
//      Math bit-identical to r27.
#define NN 20000
#define EE 160000
#define DD 128
#define GHC 512
#define INV_SQRT_HC 0.08838834764831845f  // 1/sqrt(128)

typedef __attribute__((ext_vector_type(8))) short short8;
typedef __attribute__((ext_vector_type(4))) short short4v;
typedef __attribute__((ext_vector_type(4))) float float4v;
typedef __attribute__((ext_vector_type(2))) float float2v;
typedef __attribute__((ext_vector_type(4))) unsigned uint4v;
typedef __attribute__((ext_vector_type(2))) unsigned uint2v;

__device__ inline float bf2f(unsigned short u) {
    union { unsigned u; float f; } x; x.u = ((unsigned)u) << 16; return x.f;
}
__device__ inline unsigned short f2bf(float f) {
    union { float f; unsigned u; } x; x.f = f;
    unsigned u = x.u;
    unsigned r = (u + 0x7fffu + ((u >> 16) & 1u)) >> 16;
    return (unsigned short)r;
}
// in-lane pair pack: D.lo = bf16(a), D.hi = bf16(b)  [gfx950; T12/m240 recipe]
__device__ inline unsigned cvt_pk_bf16(float a, float b) {
    unsigned d;
    asm("v_cvt_pk_bf16_f32 %0, %1, %2" : "=v"(d) : "v"(a), "v"(b));
    return d;
}

// async global->LDS 16B DMA: LDS dest must be WAVE-UNIFORM base (+lane*16 HW),
// global src is per-lane (m104/m97). Drained by the vmcnt(0) at __syncthreads.
__device__ inline void stage16(const short8* gsrc, short8* ldst) {
    __builtin_amdgcn_global_load_lds(
        (const __attribute__((address_space(1))) void*)gsrc,
        (__attribute__((address_space(3))) void*)ldst, 16, 0, 0);
}

// ---------------- fp8 e4m3 pack/unpack (HW cvt on gfx950; sw fallback) -----
#if defined(__has_builtin)
#if __has_builtin(__builtin_amdgcn_cvt_pk_f32_fp8) && __has_builtin(__builtin_amdgcn_cvt_pk_fp8_f32)
#define HW_FP8 1
#endif
#endif
#ifndef HW_FP8
#define HW_FP8 0
#endif

#if !HW_FP8
__device__ inline unsigned char sw_enc_fp8(float f) {
    if (!(f == f)) return 0x7f;
    unsigned s = (f < 0.f) ? 0x80u : 0u;
    float a = fabsf(f);
    if (a >= 448.f) return (unsigned char)(s | 0x7e);
    if (a < 5.96046448e-8f) return (unsigned char)s;
    int e; frexpf(a, &e);
    int E = e - 1;
    if (E < -6) E = -6;
    float q = ldexpf(rintf(ldexpf(a, 3 - E)), E - 3);
    if (q == 0.f) return (unsigned char)s;
    union { float f; unsigned u; } x; x.f = q;
    int qe = (int)((x.u >> 23) & 0xff) - 127;
    if (qe < -6) {
        unsigned mant = (unsigned)rintf(ldexpf(q, 9));
        return (unsigned char)(s | mant);
    }
    unsigned mant = (x.u >> 20) & 7;
    int ebits = qe + 7;
    if (ebits > 15) { ebits = 15; mant = 6; }
    return (unsigned char)(s | ((unsigned)ebits << 3) | mant);
}
__device__ inline float sw_dec_fp8(unsigned char u) {
    unsigned s = u >> 7, e = (u >> 3) & 15, m = u & 7;
    float v = e ? ldexpf((float)(8 + m), (int)e - 10) : ldexpf((float)m, -9);
    return s ? -v : v;
}
#endif

// pack 4 floats -> 4 fp8 bytes in one dword (word-sel imm per r14 lesson)
__device__ inline unsigned fp8_enc4(float a, float b, float c, float d) {
#if HW_FP8
    int r = __builtin_amdgcn_cvt_pk_fp8_f32(a, b, 0, false);
    r = __builtin_amdgcn_cvt_pk_fp8_f32(c, d, r, true);
    return (unsigned)r;
#else
    return (unsigned)sw_enc_fp8(a) | ((unsigned)sw_enc_fp8(b) << 8)
         | ((unsigned)sw_enc_fp8(c) << 16) | ((unsigned)sw_enc_fp8(d) << 24);
#endif
}
__device__ inline float2v fp8_dec2_lo(unsigned w) {
#if HW_FP8
    return __builtin_amdgcn_cvt_pk_f32_fp8((int)w, false);
#else
    float2v r;
    r[0] = sw_dec_fp8((unsigned char)(w & 0xff));
    r[1] = sw_dec_fp8((unsigned char)((w >> 8) & 0xff));
    return r;
#endif
}
__device__ inline float2v fp8_dec2_hi(unsigned w) {
#if HW_FP8
    return __builtin_amdgcn_cvt_pk_f32_fp8((int)w, true);
#else
    float2v r;
    r[0] = sw_dec_fp8((unsigned char)((w >> 16) & 0xff));
    r[1] = sw_dec_fp8((unsigned char)(w >> 24));
    return r;
#endif
}

// ---------------------------------------------------------------------------
// prep: [0,1024) convert x+te -> bf16 | [1024,1600) weight pack |
//       [1600,1664) wcomb | [1664,+EB) dst histogram.  One dispatch.
// ---------------------------------------------------------------------------
struct WPack { const void* in[18]; };
__device__ __constant__ const int WSZ[18] = {
    65536, 65536, 65536, 512, 512, 512,
    16384, 128, 65536, 512, 65536, 128,
    128, 128, 128, 128, 128, 128 };

__global__ void prep_kernel(const float* __restrict__ x, const float* __restrict__ te,
                            unsigned short* __restrict__ xcout, WPack p,
                            unsigned short* __restrict__ wcout,
                            const float* __restrict__ wv, const float* __restrict__ bv,
                            const float* __restrict__ wo, const float* __restrict__ bo,
                            unsigned short* __restrict__ wcomb,
                            unsigned short* __restrict__ bcomb,
                            const int* __restrict__ e_dst, int* __restrict__ counts)
{
    const int b = blockIdx.x;
    const int tid = threadIdx.x;
    if (b < 1024) {
        const long n4half = (long)NN * DD / 4;
        short4v* out4 = reinterpret_cast<short4v*>(xcout);
        long i = (long)b * 256 + tid;
        const long stride = 1024L * 256;
        const long tot = 2 * n4half;
        for (; i < tot; i += stride) {
            const float4v* src = (i < n4half)
                ? reinterpret_cast<const float4v*>(x)
                : reinterpret_cast<const float4v*>(te) - n4half;
            float4v v = src[i];
            short4v o;
            o[0] = (short)f2bf(v[0]); o[1] = (short)f2bf(v[1]);
            o[2] = (short)f2bf(v[2]); o[3] = (short)f2bf(v[3]);
            out4[i] = o;
        }
    } else if (b < 1600) {
        const int seg = (b - 1024) >> 5;
        const int rep = (b - 1024) & 31;
        int off = 0;
#pragma unroll
        for (int s = 0; s < 18; ++s) if (s < seg) off += WSZ[s];
        const int n = WSZ[seg];
        const float* q = (const float*)p.in[seg];
        for (int i = rep * 256 + tid; i < n; i += 32 * 256)
            wcout[off + i] = f2bf(q[i]);
    } else if (b < 1664) {
        int e = (b - 1600) * 256 + tid;   // 16384 total
        int i = e >> 7, kk = e & 127;
        float s = 0.f;
        for (int j = 0; j < 128; ++j)
            s += wo[i * 128 + j] * wv[j * 128 + kk];
        wcomb[e] = f2bf(s);
        if (b == 1600 && tid < 128) {
            float t = 0.f;
            for (int j = 0; j < 128; ++j) t += wo[tid * 128 + j] * bv[j];
            bcomb[tid] = f2bf(t + bo[tid]);
        }
    } else {
        int e = (b - 1664) * 256 + tid;
        if (e < EE) {
            int d = e_dst[e];
            if (d >= 0 && d < NN) atomicAdd(&counts[d], 1);
        }
    }
}

// ---------------------------------------------------------------------------
// GEMM v6 (r20, BEST): K=128, 128 cols/block, 256 rows/block = 4 row-tiles,
// SWAPPED operands mfma(W,x) -> lane holds row m=l&15, 4 consecutive cols.
// In-lane cvt_pk epilogues -> XOR-swizzled LDS -> b128 stores. W slab (32KB)
// staged once via global_load_lds DMA; LDS 40960 = 4 blk/CU. Bijective
// XCD-chunked 1D remap. cols < split -> bf16 out; >= split -> fp8 kv rows.
// ---------------------------------------------------------------------------
__global__ __launch_bounds__(256) void gemm3_kernel(
    const unsigned short* __restrict__ A, const unsigned short* __restrict__ W,
    const unsigned short* __restrict__ bias, unsigned short* __restrict__ out,
    unsigned char* __restrict__ kvout, int M, int Nout, int split, int relu,
    int nxg, int ncol)
{
    __shared__ short8 wslab[2048];                                       // 32 KB
    __shared__ __attribute__((aligned(16))) unsigned stile4[4][16][32];  //  8 KB
    const int tid  = threadIdx.x;
    const int lane = tid & 63;
    const int wid  = tid >> 6;
    const int quad = lane >> 4;
    const int l15  = lane & 15;

    // bijective XCD-chunked remap (m204)
    const int nb  = nxg * ncol;
    const int qq  = nb >> 3, rm = nb & 7;
    const int xcd = blockIdx.x & 7, slot = blockIdx.x >> 3;
    const int c   = (xcd < rm) ? xcd * (qq + 1) + slot
                               : rm * (qq + 1) + (xcd - rm) * qq + slot;
    const int xg = c / ncol;              // row-group (256 rows)
    const int yg = c - xg * ncol;         // col-slab
    const int colbase0 = yg * 128;
    const int rowg = xg * 256;

    const bool isfp8 = (colbase0 >= split);
    const int kvcol = colbase0 - split;              // 0..1023 when fp8
    const int which = isfp8 ? (kvcol >> 9) : 0;      // 0=k, 1=v
    const int head  = isfp8 ? ((kvcol & 511) >> 7) : 0;

    const short8* A8 = reinterpret_cast<const short8*>(A);
    const short8* W8 = reinterpret_cast<const short8*>(W);

    // tile-0 A loads issued first: latency hides under W staging
    short8 a4[4];
    {
        int arow = rowg + wid * 16 + l15;
        if (arow >= M) arow = M - 1;
#pragma unroll
        for (int i = 0; i < 4; ++i) a4[i] = A8[(size_t)arow * 16 + i * 4 + quad];
    }

    // W slab DMA: LDS element f = rep*256 + wid*64 + lane (wave-linear)
#pragma unroll
    for (int rep = 0; rep < 8; ++rep) {
        const int fi  = (rep * 4 + wid) & 3;
        const int ft  = rep & 3;
        const int ftt = rep >> 2;
        const int wrow = colbase0 + ftt * 64 + 16 * ft + l15;
        stage16(&W8[(size_t)wrow * 16 + fi * 4 + quad], &wslab[rep * 256 + wid * 64]);
    }

    // per-lane bias: 4 consecutive cols per (tt,t) at n0 = tt*64+16t+quad*4
    short4v bs4[2][4];
#pragma unroll
    for (int tt = 0; tt < 2; ++tt)
#pragma unroll
        for (int t = 0; t < 4; ++t)
            bs4[tt][t] = *reinterpret_cast<const short4v*>(
                &bias[colbase0 + tt * 64 + 16 * t + quad * 4]);

    __syncthreads();

    unsigned* fpd = &stile4[wid][0][0];   // dword view, per-wave 2 KB

#pragma unroll
    for (int tg = 0; tg < 4; ++tg) {
        const int rowbase = rowg + tg * 64 + wid * 16;

        // prefetch next tile's A under this tile's compute
        short8 a4n[4];
        if (tg < 3) {
            int arow = rowbase + 64 + l15;
            if (arow >= M) arow = M - 1;
#pragma unroll
            for (int i = 0; i < 4; ++i) a4n[i] = A8[(size_t)arow * 16 + i * 4 + quad];
        }

#pragma unroll
        for (int tt = 0; tt < 2; ++tt) {
            float4v acc[4];
#pragma unroll
            for (int t = 0; t < 4; ++t) acc[t] = (float4v){0.f, 0.f, 0.f, 0.f};

#pragma unroll
            for (int i = 0; i < 4; ++i) {
#pragma unroll
                for (int t = 0; t < 4; ++t) {
                    short8 wb = wslab[((tt * 4 + t) * 4 + i) * 64 + lane];
                    acc[t] = __builtin_amdgcn_mfma_f32_16x16x32_bf16(wb, a4[i], acc[t], 0, 0, 0);
                }
            }

            if (!isfp8) {
                // in-lane pack: 2 dwords (4 bf16 cols) per (t); XOR-swizzled LDS
#pragma unroll
                for (int t = 0; t < 4; ++t) {
                    float v0 = acc[t][0] + bf2f((unsigned short)bs4[tt][t][0]);
                    float v1 = acc[t][1] + bf2f((unsigned short)bs4[tt][t][1]);
                    float v2 = acc[t][2] + bf2f((unsigned short)bs4[tt][t][2]);
                    float v3 = acc[t][3] + bf2f((unsigned short)bs4[tt][t][3]);
                    if (relu) {
                        v0 = fmaxf(v0, 0.f); v1 = fmaxf(v1, 0.f);
                        v2 = fmaxf(v2, 0.f); v3 = fmaxf(v3, 0.f);
                    }
                    uint2v d = { cvt_pk_bf16(v0, v1), cvt_pk_bf16(v2, v3) };
                    const int dc = (8 * t + quad * 2) ^ ((l15 & 7) << 2);
                    *reinterpret_cast<uint2v*>(&stile4[wid][l15][dc]) = d;
                }
                const int rr0 = lane >> 3;
                const int cd  = (lane & 7) * 4;
#pragma unroll
                for (int it = 0; it < 2; ++it) {
                    int rw = rr0 + it * 8;
                    int grow = rowbase + rw;
                    if (grow < M) {
                        const int cs = cd ^ ((rw & 7) << 2);
                        uint4v v = *reinterpret_cast<const uint4v*>(&stile4[wid][rw][cs]);
                        *reinterpret_cast<uint4v*>(&out[(size_t)grow * Nout + colbase0 + tt * 64 + cd * 2]) = v;
                    }
                }
            } else {
                // fp8: in-lane 4-byte pack per (t); XOR-swizzled dword stage
#pragma unroll
                for (int t = 0; t < 4; ++t) {
                    float v0 = (acc[t][0] + bf2f((unsigned short)bs4[tt][t][0])) * 256.f;
                    float v1 = (acc[t][1] + bf2f((unsigned short)bs4[tt][t][1])) * 256.f;
                    float v2 = (acc[t][2] + bf2f((unsigned short)bs4[tt][t][2])) * 256.f;
                    float v3 = (acc[t][3] + bf2f((unsigned short)bs4[tt][t][3])) * 256.f;
                    const int dc = (tt * 16 + 4 * t + quad) ^ ((l15 & 7) << 2);
                    fpd[l15 * 32 + dc] = fp8_enc4(v0, v1, v2, v3);
                }
            }
        }

        if (isfp8) {
            // one store pass: 16 rows x 128B contiguous (full cache lines)
#pragma unroll
            for (int it = 0; it < 2; ++it) {
                int u = lane + it * 64;          // 0..127
                int row = u >> 3;                // 0..15
                int part = u & 7;                // 0..7 (16B each)
                int grow = rowbase + row;
                if (grow < M) {
                    const int db = row * 32 + ((part * 4) ^ ((row & 7) << 2));
                    uint4v v = *reinterpret_cast<const uint4v*>(&fpd[db]);
                    size_t ro = (size_t)grow * 1024 + (size_t)which * 512
                              + (size_t)head * 128 + (size_t)part * 16;
                    *reinterpret_cast<uint4v*>(kvout + ro) = v;
                }
            }
        }

        if (tg < 3) {
#pragma unroll
            for (int i = 0; i < 4; ++i) a4[i] = a4n[i];
        }
    }
}

// stage a 128-row W block: rows RO+wrow, row stride RS8 short8s, col off CO8
#define STAGE_W(W8, RS8, CO8, RO, WS) do {                                    \
    _Pragma("unroll")                                                         \
    for (int rep_ = 0; rep_ < 8; ++rep_) {                                    \
        const int fi_  = (rep_ * 4 + wid) & 3;                                \
        const int ft_  = rep_ & 3;                                            \
        const int ftt_ = rep_ >> 2;                                           \
        const int wrow_ = (RO) + ftt_ * 64 + 16 * ft_ + l15;                  \
        stage16(&(W8)[(size_t)wrow_ * (RS8) + (CO8) + fi_ * 4 + quad],        \
                &(WS)[rep_ * 256 + wid * 64]);                                \
    } } while (0)

// acc[2][4] += ws(128x128) @ frags
#define MM128(WS, AF, ACC) do {                                               \
    _Pragma("unroll")                                                         \
    for (int tt_ = 0; tt_ < 2; ++tt_)                                         \
    _Pragma("unroll")                                                         \
    for (int i_ = 0; i_ < 4; ++i_)                                            \
    _Pragma("unroll")                                                         \
    for (int t_ = 0; t_ < 4; ++t_) {                                          \
        short8 wb_ = (WS)[((tt_ * 4 + t_) * 4 + i_) * 64 + lane];             \
        (ACC)[tt_][t_] = __builtin_amdgcn_mfma_f32_16x16x32_bf16(             \
            wb_, (AF)[i_], (ACC)[tt_][t_], 0, 0, 0);                          \
    } } while (0)

// ---------------------------------------------------------------------------
// TAIL (r28): r27 math with DOUBLE-BUFFERED W staging.
//   wsA role: gs_w, then F1 chunks.  wsB role: wcomb, then F2 chunks.
//   stage(next) issued BEFORE the current buffer's MFMA phase; each barrier
//   = {consumers of restaged buffer done} + {new DMA drained after a full
//   compute phase of latency hiding}. Barriers ~11 (was ~19).
// LDS = 2x32KB wslab + 16KB htile = 80KB -> 2 blk/CU; grid 313 (~1.2/CU).
// ---------------------------------------------------------------------------
__global__ __launch_bounds__(256) void tail_kernel(
    const unsigned short* __restrict__ A1, const unsigned short* __restrict__ W1g,
    const unsigned short* __restrict__ b1g,
    const unsigned short* __restrict__ A2, const unsigned short* __restrict__ W2g,
    const unsigned short* __restrict__ b2g,
    const float* __restrict__ rx, const float* __restrict__ ragg,
    const unsigned short* __restrict__ g1, const unsigned short* __restrict__ be1,
    const unsigned short* __restrict__ g2, const unsigned short* __restrict__ be2,
    const unsigned short* __restrict__ fw1, const unsigned short* __restrict__ fb1,
    const unsigned short* __restrict__ fw2, const unsigned short* __restrict__ fb2,
    const unsigned short* __restrict__ g3, const unsigned short* __restrict__ be3,
    float* __restrict__ outf, int M)
{
    __shared__ short8 wsA[2048];                                          // 32 KB
    __shared__ short8 wsB[2048];                                          // 32 KB
    __shared__ __attribute__((aligned(16))) unsigned short htile[64 * 128]; // 16 KB
    const int tid  = threadIdx.x;
    const int lane = tid & 63;
    const int wid  = tid >> 6;
    const int quad = lane >> 4;
    const int l15  = lane & 15;
    const int rowbase = blockIdx.x * 64 + wid * 16;
    const int grow = rowbase + l15;
    const int gr = (grow < M) ? grow : M - 1;
    const int hrow = wid * 16 + l15;      // htile row (wave-private)
    char* hb = reinterpret_cast<char*>(htile);

    const short8* A81 = reinterpret_cast<const short8*>(A1);
    const short8* A82 = reinterpret_cast<const short8*>(A2);
    const short8* W81 = reinterpret_cast<const short8*>(W1g);
    const short8* W82 = reinterpret_cast<const short8*>(W2g);
    const short8* F18 = reinterpret_cast<const short8*>(fw1);  // 16 short8/row
    const short8* F28 = reinterpret_cast<const short8*>(fw2);  // 64 short8/row

    // ---- P0: stage gs_w->A AND wcomb->B; load both frag sets ----
    STAGE_W(W81, 16, 0, 0, wsA);
    STAGE_W(W82, 16, 0, 0, wsB);
    short8 a4[4], a42[4];
#pragma unroll
    for (int i = 0; i < 4; ++i) {
        a4[i]  = A81[(size_t)gr * 16 + i * 4 + quad];
        a42[i] = A82[(size_t)gr * 16 + i * 4 + quad];
    }
    __syncthreads();   // A(gs_w) + B(wcomb) staged

    // ---- P1: MFMA1 from A ----
    float4v acc1[2][4];
#pragma unroll
    for (int tt = 0; tt < 2; ++tt)
#pragma unroll
        for (int t = 0; t < 4; ++t) acc1[tt][t] = (float4v){0.f, 0.f, 0.f, 0.f};
    MM128(wsA, a4, acc1);
    __syncthreads();   // all waves done reading A

    // issue F1 chunk0 -> A; its latency hides under LN1 + MFMA2
    STAGE_W(F18, 16, 0, 0, wsA);

    // ---- LN1 in registers ----
    float x1[32];
    {
        float v[32];
#pragma unroll
        for (int tt = 0; tt < 2; ++tt)
#pragma unroll
            for (int t = 0; t < 4; ++t) {
                const int n0 = tt * 64 + 16 * t + quad * 4;
                short4v bs = *reinterpret_cast<const short4v*>(&b1g[n0]);
                float4v rv = *reinterpret_cast<const float4v*>(&rx[(size_t)gr * 128 + n0]);
                float4v cv = *reinterpret_cast<const float4v*>(&ragg[(size_t)gr * 128 + n0]);
#pragma unroll
                for (int r = 0; r < 4; ++r)
                    v[(tt * 4 + t) * 4 + r] = acc1[tt][t][r]
                        + bf2f((unsigned short)bs[r]) + rv[r] + cv[r];
            }
        float s = 0.f, sq = 0.f;
#pragma unroll
        for (int i = 0; i < 32; ++i) { s += v[i]; sq += v[i] * v[i]; }
        s  += __shfl_xor(s, 16, 64);  s  += __shfl_xor(s, 32, 64);
        sq += __shfl_xor(sq, 16, 64); sq += __shfl_xor(sq, 32, 64);
        float mu  = s * (1.f / 128.f);
        float var = sq * (1.f / 128.f) - mu * mu;
        float rs  = rsqrtf(fmaxf(var, 0.f) + 1e-5f);
#pragma unroll
        for (int tt = 0; tt < 2; ++tt)
#pragma unroll
            for (int t = 0; t < 4; ++t) {
                const int n0 = tt * 64 + 16 * t + quad * 4;
                short4v gg = *reinterpret_cast<const short4v*>(&g1[n0]);
                short4v bb = *reinterpret_cast<const short4v*>(&be1[n0]);
#pragma unroll
                for (int r = 0; r < 4; ++r)
                    x1[(tt * 4 + t) * 4 + r] = (v[(tt * 4 + t) * 4 + r] - mu) * rs
                        * bf2f((unsigned short)gg[r]) + bf2f((unsigned short)bb[r]);
            }
    }

    // ---- MFMA2 from B, LN2 -> x2 ----
    float4v acc2[2][4];
#pragma unroll
    for (int tt = 0; tt < 2; ++tt)
#pragma unroll
        for (int t = 0; t < 4; ++t) acc2[tt][t] = (float4v){0.f, 0.f, 0.f, 0.f};
    MM128(wsB, a42, acc2);

    float x2[32];
    {
        float v[32];
#pragma unroll
        for (int tt = 0; tt < 2; ++tt)
#pragma unroll
            for (int t = 0; t < 4; ++t) {
                const int n0 = tt * 64 + 16 * t + quad * 4;
                short4v bs = *reinterpret_cast<const short4v*>(&b2g[n0]);
#pragma unroll
                for (int r = 0; r < 4; ++r)
                    v[(tt * 4 + t) * 4 + r] = acc2[tt][t][r]
                        + bf2f((unsigned short)bs[r]) + x1[(tt * 4 + t) * 4 + r];
            }
        float s = 0.f, sq = 0.f;
#pragma unroll
        for (int i = 0; i < 32; ++i) { s += v[i]; sq += v[i] * v[i]; }
        s  += __shfl_xor(s, 16, 64);  s  += __shfl_xor(s, 32, 64);
        sq += __shfl_xor(sq, 16, 64); sq += __shfl_xor(sq, 32, 64);
        float mu  = s * (1.f / 128.f);
        float var = sq * (1.f / 128.f) - mu * mu;
        float rs  = rsqrtf(fmaxf(var, 0.f) + 1e-5f);
#pragma unroll
        for (int tt = 0; tt < 2; ++tt)
#pragma unroll
            for (int t = 0; t < 4; ++t) {
                const int n0 = tt * 64 + 16 * t + quad * 4;
                short4v gg = *reinterpret_cast<const short4v*>(&g2[n0]);
                short4v bb = *reinterpret_cast<const short4v*>(&be2[n0]);
#pragma unroll
                for (int r = 0; r < 4; ++r)
                    x2[(tt * 4 + t) * 4 + r] = (v[(tt * 4 + t) * 4 + r] - mu) * rs
                        * bf2f((unsigned short)gg[r]) + bf2f((unsigned short)bb[r]);
            }
    }

    // ---- x2 -> htile (wave-private rows, r21 swizzle); read A-fragments ----
#pragma unroll
    for (int tt = 0; tt < 2; ++tt)
#pragma unroll
        for (int t = 0; t < 4; ++t) {
            const int n0 = tt * 64 + 16 * t + quad * 4;
            const int idx = (tt * 4 + t) * 4;
            uint2v d = { cvt_pk_bf16(x2[idx], x2[idx + 1]),
                         cvt_pk_bf16(x2[idx + 2], x2[idx + 3]) };
            *reinterpret_cast<uint2v*>(
                hb + ((hrow * 256 + n0 * 2) ^ ((hrow & 7) << 4))) = d;
        }
    short8 af[4];
#pragma unroll
    for (int i = 0; i < 4; ++i)
        af[i] = *reinterpret_cast<const short8*>(
            hb + ((hrow * 256 + (i * 32 + quad * 8) * 2) ^ ((hrow & 7) << 4)));

    __syncthreads();   // A ready (F1c0); all waves done reading B

    // ---- FFN loop: A = F1[cc], B = F2[cc], double-buffered stages ----
    float4v accf[2][4];
#pragma unroll
    for (int tt = 0; tt < 2; ++tt)
#pragma unroll
        for (int t = 0; t < 4; ++t) accf[tt][t] = (float4v){0.f, 0.f, 0.f, 0.f};

    for (int cc = 0; cc < 4; ++cc) {
        // issue F2[cc] -> B; latency hides under up-gemm from A
        STAGE_W(F28, 64, cc * 16, 0, wsB);

        // up-gemm: h = relu(x2 @ F1[cc] + b1), write own htile rows
        float4v au[2][4];
#pragma unroll
        for (int tt = 0; tt < 2; ++tt)
#pragma unroll
            for (int t = 0; t < 4; ++t) au[tt][t] = (float4v){0.f, 0.f, 0.f, 0.f};
        MM128(wsA, af, au);
#pragma unroll
        for (int tt = 0; tt < 2; ++tt)
#pragma unroll
            for (int t = 0; t < 4; ++t) {
                const int n0 = tt * 64 + 16 * t + quad * 4;
                short4v bs = *reinterpret_cast<const short4v*>(&fb1[cc * 128 + n0]);
                float v0 = fmaxf(au[tt][t][0] + bf2f((unsigned short)bs[0]), 0.f);
                float v1 = fmaxf(au[tt][t][1] + bf2f((unsigned short)bs[1]), 0.f);
                float v2 = fmaxf(au[tt][t][2] + bf2f((unsigned short)bs[2]), 0.f);
                float v3 = fmaxf(au[tt][t][3] + bf2f((unsigned short)bs[3]), 0.f);
                uint2v d = { cvt_pk_bf16(v0, v1), cvt_pk_bf16(v2, v3) };
                *reinterpret_cast<uint2v*>(
                    hb + ((hrow * 256 + n0 * 2) ^ ((hrow & 7) << 4))) = d;
            }
        __syncthreads();   // B ready (F2[cc]); all waves done reading A

        // issue F1[cc+1] -> A; latency hides under down-gemm from B
        if (cc < 3) STAGE_W(F18, 16, 0, (cc + 1) * 128, wsA);

        // down-gemm: accf += h @ F2[cc]^T (h read from own htile rows)
        short8 h4[4];
#pragma unroll
        for (int i = 0; i < 4; ++i)
            h4[i] = *reinterpret_cast<const short8*>(
                hb + ((hrow * 256 + (i * 32 + quad * 8) * 2) ^ ((hrow & 7) << 4)));
        MM128(wsB, h4, accf);
        __syncthreads();   // A ready (F1[cc+1]); all waves done reading B
    }

    // ---- LN3 epilogue in regs (residual = x2 in regs) ----
    float v[32];
#pragma unroll
    for (int tt = 0; tt < 2; ++tt)
#pragma unroll
        for (int t = 0; t < 4; ++t) {
            const int n0 = tt * 64 + 16 * t + quad * 4;
            short4v bs = *reinterpret_cast<const short4v*>(&fb2[n0]);
#pragma unroll
            for (int r = 0; r < 4; ++r)
                v[(tt * 4 + t) * 4 + r] = accf[tt][t][r]
                    + bf2f((unsigned short)bs[r]) + x2[(tt * 4 + t) * 4 + r];
        }
    float s = 0.f, sq = 0.f;
#pragma unroll
    for (int i = 0; i < 32; ++i) { s += v[i]; sq += v[i] * v[i]; }
    s  += __shfl_xor(s, 16, 64);  s  += __shfl_xor(s, 32, 64);
    sq += __shfl_xor(sq, 16, 64); sq += __shfl_xor(sq, 32, 64);
    float mu  = s * (1.f / 128.f);
    float var = sq * (1.f / 128.f) - mu * mu;
    float rs  = rsqrtf(fmaxf(var, 0.f) + 1e-5f);

    if (grow < M) {
#pragma unroll
        for (int tt = 0; tt < 2; ++tt)
#pragma unroll
            for (int t = 0; t < 4; ++t) {
                const int n0 = tt * 64 + 16 * t + quad * 4;
                short4v gg = *reinterpret_cast<const short4v*>(&g3[n0]);
                short4v bb = *reinterpret_cast<const short4v*>(&be3[n0]);
                float4v ov;
#pragma unroll
                for (int r = 0; r < 4; ++r)
                    ov[r] = (v[(tt * 4 + t) * 4 + r] - mu) * rs
                            * bf2f((unsigned short)gg[r]) + bf2f((unsigned short)bb[r]);
                *reinterpret_cast<float4v*>(&outf[(size_t)grow * 128 + n0]) = ov;
            }
    }
}

// ---------------------------------------------------------------------------
// CSR scan + scatter (r20 proven versions)
// ---------------------------------------------------------------------------
__global__ __launch_bounds__(1024) void scan_kernel(
    const int* __restrict__ counts, int* __restrict__ offsets, int* __restrict__ pos, int n)
{
    __shared__ int wsum[16];
    __shared__ int carry_s;
    const int tid = threadIdx.x;
    const int wid = tid >> 6, lane = tid & 63;
    int vals[20];
#pragma unroll
    for (int cI = 0; cI < 20; ++cI) {
        int i = cI * 1024 + tid;
        vals[cI] = (i < n) ? counts[i] : 0;
    }
    if (tid == 0) carry_s = 0;
    __syncthreads();
#pragma unroll
    for (int cI = 0; cI < 20; ++cI) {
        int i = cI * 1024 + tid;
        int val = vals[cI];
        int x = val;
#pragma unroll
        for (int off = 1; off < 64; off <<= 1) {
            int t = __shfl_up(x, off, 64);
            if (lane >= off) x += t;
        }
        if (lane == 63) wsum[wid] = x;
        __syncthreads();
        if (wid == 0 && lane < 16) {
            int s = wsum[lane];
#pragma unroll
            for (int off = 1; off < 16; off <<= 1) {
                int t = __shfl_up(s, off, 64);
                if (lane >= off) s += t;
            }
            wsum[lane] = s;
        }
        __syncthreads();
        int prefix = (wid > 0 ? wsum[wid - 1] : 0) + carry_s;
        int ex = prefix + x - val;
        if (i < n) { offsets[i] = ex; pos[i] = ex; }
        __syncthreads();
        if (tid == 0) carry_s += wsum[15];
        __syncthreads();
    }
    if (tid == 0) offsets[n] = carry_s;
}

__global__ void scatter_kernel(const int* __restrict__ src, const int* __restrict__ dst,
                               int* __restrict__ pos, int* __restrict__ sorted_src, int E)
{
    int e = blockIdx.x * 256 + threadIdx.x;
    if (e < E) {
        int d = dst[e];
        if (d >= 0 && d < NN) {
            int p = atomicAdd(&pos[d], 1);
            if (p >= 0 && p < E) sorted_src[p] = src[e];
        }
    }
}

// ---------------------------------------------------------------------------
// All-heads graph attention over fp8 kv (r26): 2 waves/node, 4-deep load
// groups, sacc padded [..][9] (conflict-free publish, measured r25 2.88M).
// ---------------------------------------------------------------------------
__device__ inline void agg_edge(const uint2v& kk, const uint2v& vv,
                                const float* qf, float* acc, float& ssum)
{
    float2v k01 = fp8_dec2_lo(kk[0]);
    float2v k23 = fp8_dec2_hi(kk[0]);
    float2v k45 = fp8_dec2_lo(kk[1]);
    float2v k67 = fp8_dec2_hi(kk[1]);
    float dot = qf[0] * k01[0] + qf[1] * k01[1] + qf[2] * k23[0] + qf[3] * k23[1]
              + qf[4] * k45[0] + qf[5] * k45[1] + qf[6] * k67[0] + qf[7] * k67[1];
    dot += __shfl_xor(dot, 1, 64);
    dot += __shfl_xor(dot, 2, 64);
    dot += __shfl_xor(dot, 4, 64);
    dot += __shfl_xor(dot, 8, 64);
    float pp = __expf(dot);
    ssum += pp;
    float2v v01 = fp8_dec2_lo(vv[0]);
    float2v v23 = fp8_dec2_hi(vv[0]);
    float2v v45 = fp8_dec2_lo(vv[1]);
    float2v v67 = fp8_dec2_hi(vv[1]);
    acc[0] += pp * v01[0]; acc[1] += pp * v01[1];
    acc[2] += pp * v23[0]; acc[3] += pp * v23[1];
    acc[4] += pp * v45[0]; acc[5] += pp * v45[1];
    acc[6] += pp * v67[0]; acc[7] += pp * v67[1];
}

__global__ __launch_bounds__(256) void agg_kernel(
    const unsigned short* __restrict__ q, const unsigned char* __restrict__ kvb,
    const int* __restrict__ offsets, const int* __restrict__ srcs,
    float* __restrict__ aggb)
{
    __shared__ float sacc[4][64][9];     // padded: conflict-free publish
    __shared__ float sssum[4][64];
    const int tid  = threadIdx.x;
    const int wid  = tid >> 6;
    const int lane = tid & 63;
    const int node = blockIdx.x * 2 + (wid >> 1);
    const int half = wid & 1;

    const short8* q8 = reinterpret_cast<const short8*>(q);
    const int fidx = (lane >> 4) * 16 + (lane & 15);
    const int koff = fidx * 8;            // head*128 + sub*8

    short8 qv = q8[(size_t)node * 64 + fidx];
    float qf[8];
#pragma unroll
    for (int i = 0; i < 8; ++i)
        qf[i] = bf2f((unsigned short)qv[i]) * (INV_SQRT_HC / 256.f);

    int beg = offsets[node], end = offsets[node + 1];
    if (beg < 0) beg = 0;
    if (end > EE) end = EE;
    float ssum = 0.f;
    float acc[8];
#pragma unroll
    for (int i = 0; i < 8; ++i) acc[i] = 0.f;

    const int start = beg + half;
    int nce = (end > start) ? ((end - start + 1) >> 1) : 0;
    int ncap = (nce > 64) ? 64 : nce;

    int sv = 0;
    if (lane < ncap) {
        int s = srcs[start + 2 * lane];
        if (s < 0) s = 0;
        if (s >= NN) s = NN - 1;
        sv = s;
    }
    // groups of 4: issue all loads, then compute (4 outstanding L3 reqs)
    for (int base = 0; base < ncap; base += 4) {
        const int rem = ncap - base;
        uint2v k0{}, v0{}, k1{}, v1{}, k2{}, v2{}, k3{}, v3{};
        {
            int s = __shfl(sv, base, 64);
            const unsigned char* p = kvb + (size_t)s * 1024 + koff;
            k0 = *reinterpret_cast<const uint2v*>(p);
            v0 = *reinterpret_cast<const uint2v*>(p + 512);
        }
        if (rem > 1) {
            int s = __shfl(sv, base + 1, 64);
            const unsigned char* p = kvb + (size_t)s * 1024 + koff;
            k1 = *reinterpret_cast<const uint2v*>(p);
            v1 = *reinterpret_cast<const uint2v*>(p + 512);
        }
        if (rem > 2) {
            int s = __shfl(sv, base + 2, 64);
            const unsigned char* p = kvb + (size_t)s * 1024 + koff;
            k2 = *reinterpret_cast<const uint2v*>(p);
            v2 = *reinterpret_cast<const uint2v*>(p + 512);
        }
        if (rem > 3) {
            int s = __shfl(sv, base + 3, 64);
            const unsigned char* p = kvb + (size_t)s * 1024 + koff;
            k3 = *reinterpret_cast<const uint2v*>(p);
            v3 = *reinterpret_cast<const uint2v*>(p + 512);
        }
        agg_edge(k0, v0, qf, acc, ssum);
        if (rem > 1) agg_edge(k1, v1, qf, acc, ssum);
        if (rem > 2) agg_edge(k2, v2, qf, acc, ssum);
        if (rem > 3) agg_edge(k3, v3, qf, acc, ssum);
    }
    for (int j = start + 128; j < end; j += 2) {   // pathological-degree tail
        int s = srcs[j];
        if (s < 0) s = 0;
        if (s >= NN) s = NN - 1;
        uint2v kc = *reinterpret_cast<const uint2v*>(kvb + (size_t)s * 1024 + koff);
        uint2v vc = *reinterpret_cast<const uint2v*>(kvb + (size_t)s * 1024 + 512 + koff);
        agg_edge(kc, vc, qf, acc, ssum);
    }

    // publish partials; even wave combines
#pragma unroll
    for (int i = 0; i < 8; ++i) sacc[wid][lane][i] = acc[i];
    sssum[wid][lane] = ssum;
    __syncthreads();
    if (half == 0) {
#pragma unroll
        for (int i = 0; i < 8; ++i) acc[i] += sacc[wid ^ 1][lane][i];
        ssum += sssum[wid ^ 1][lane];

        float inv = (ssum > 0.f) ? 1.f / (256.f * ssum) : 0.f;   // undo x256
#pragma unroll
        for (int i = 0; i < 8; ++i) acc[i] *= inv;
#pragma unroll
        for (int i = 0; i < 8; ++i) {
            acc[i] += __shfl_xor(acc[i], 16, 64);
            acc[i] += __shfl_xor(acc[i], 32, 64);
            acc[i] *= 0.25f;
        }
        if (lane < 16) {
            float4v* o = reinterpret_cast<float4v*>(aggb + (size_t)node * 128 + lane * 8);
            o[0] = (float4v){acc[0], acc[1], acc[2], acc[3]};
            o[1] = (float4v){acc[4], acc[5], acc[6], acc[7]};
        }
    }
}

// ---------------------------------------------------------------------------
extern "C" void kernel_launch(void* const* d_in, const int* in_sizes, int n_in,
                              void* d_out, int out_size, void* d_ws, size_t ws_size,
                              hipStream_t stream)
{
    const int* edge_index = (const int*)d_in[28];
    const int* e_src = edge_index;
    const int* e_dst = edge_index + EE;

    if (n_in < 29 || in_sizes[0] != NN * DD || in_sizes[28] != 2 * EE || out_size != NN * DD)
        return;

    const size_t SZ_OFF  = (size_t)(NN + 16) * 4;
    const size_t SZ_CNT  = (size_t)NN * 4;
    const size_t SZ_SS   = (size_t)EE * 4;
    const size_t SZ_SM   = (size_t)NN * DD * 2;     //  5.12 MB
    const size_t SZ_F32  = (size_t)NN * DD * 4;     // 10.24 MB
    const size_t SZ_Q    = (size_t)NN * 512 * 2;    // 20.48 MB
    const size_t SZ_KV   = (size_t)NN * 1024;       // 20.48 MB (fp8)
    const size_t SZ_HB   = (size_t)NN * GHC * 2;    // 20.48 MB (unused, kept)
    const size_t WC_ELE  = 347136;
    const size_t SZ_WC   = WC_ELE * 2;
    const size_t SZ_WCB  = 16384 * 2 + 256;
    const size_t REQUIRED = SZ_OFF + 2 * SZ_CNT + SZ_SS + 2 * SZ_SM + SZ_WC + SZ_WCB
                          + SZ_Q + SZ_KV + 3 * SZ_F32 + SZ_SM + SZ_HB;

    if (ws_size < REQUIRED) return;

    char* w = (char*)d_ws;
    int* offsets = (int*)w;        w += SZ_OFF;
    int* counts  = (int*)w;        w += SZ_CNT;
    int* pos     = (int*)w;        w += SZ_CNT;
    int* sorted_src = (int*)w;     w += SZ_SS;
    unsigned short* xc   = (unsigned short*)w; w += SZ_SM;
    unsigned short* tec  = (unsigned short*)w; w += SZ_SM;
    unsigned short* wc   = (unsigned short*)w; w += SZ_WC;
    unsigned short* wcomb = (unsigned short*)w; w += 16384 * 2;
    unsigned short* bcomb = (unsigned short*)w; w += 256;
    unsigned short* qb   = (unsigned short*)w; w += SZ_Q;
    unsigned char*  kvb  = (unsigned char*)w;  w += SZ_KV;
    float*          aggb = (float*)w;          w += SZ_F32;
    float*          x1f  = (float*)w;          w += SZ_F32;   // unused (kept layout)
    float*          x2f  = (float*)w;          w += SZ_F32;   // unused (kept layout)
    unsigned short* x2b  = (unsigned short*)w; w += SZ_SM;    // unused (kept layout)
    unsigned short* hbuf = (unsigned short*)w; w += SZ_HB;    // unused (kept layout)
    (void)x1f; (void)x2f; (void)x2b; (void)hbuf;

    unsigned short* cw = wc;
    unsigned short* qkv_w = cw; cw += 3 * 65536;
    unsigned short* qkv_b = cw; cw += 3 * 512;
    unsigned short* gs_w  = cw; cw += 16384;  unsigned short* gs_b  = cw; cw += 128;
    unsigned short* ffn_w1 = cw; cw += 65536; unsigned short* ffn_b1 = cw; cw += 512;
    unsigned short* ffn_w2 = cw; cw += 65536; unsigned short* ffn_b2 = cw; cw += 128;
    unsigned short* ln1_g = cw; cw += 128;    unsigned short* ln1_b = cw; cw += 128;
    unsigned short* ln2_g = cw; cw += 128;    unsigned short* ln2_b = cw; cw += 128;
    unsigned short* ln3_g = cw; cw += 128;    unsigned short* ln3_b = cw; cw += 128;

    const int EB = (EE + 255) / 256;
    const dim3 blk(256);
    const int MB = (NN + 63) / 64;            // 313
    const int MB2 = (NN + 255) / 256;         // 79

    WPack pack;
    const int live_idx[18] = {2,4,6, 3,5,7, 8,9, 18,19, 20,21, 22,23,24,25,26,27};
    for (int i = 0; i < 18; ++i) pack.in[i] = d_in[live_idx[i]];

    (void)hipMemsetAsync(counts, 0, SZ_CNT, stream);
    prep_kernel<<<1664 + EB, blk, 0, stream>>>((const float*)d_in[0], (const float*)d_in[1],
                                               xc, pack, wc,
                                               (const float*)d_in[14], (const float*)d_in[15],
                                               (const float*)d_in[16], (const float*)d_in[17],
                                               wcomb, bcomb, e_dst, counts);

    scan_kernel<<<1, 1024, 0, stream>>>(counts, offsets, pos, NN);
    scatter_kernel<<<EB, blk, 0, stream>>>(e_src, e_dst, pos, sorted_src, EE);

    // TransformerConv: QKV (q bf16 -> qb; k|v fp8 -> kvb), agg
    gemm3_kernel<<<dim3(MB2 * 12), blk, 0, stream>>>(xc, qkv_w, qkv_b, qb, kvb,
                                                     NN, 512, 512, 0, MB2, 12);
    agg_kernel<<<NN / 2, blk, 0, stream>>>(qb, kvb, offsets, sorted_src, aggb);

    // TAIL: ln12 + FFN + LN3 fused (row-local, double-buffered W) -> d_out
    tail_kernel<<<MB, blk, 0, stream>>>(xc, gs_w, gs_b,
                                        tec, wcomb, bcomb,
                                        (const float*)d_in[0], aggb,
                                        ln1_g, ln1_b, ln2_g, ln2_b,
                                        ffn_w1, ffn_b1, ffn_w2, ffn_b2,
                                        ln3_g, ln3_b, (float*)d_out, NN);
}

// Round 13
// 234.983 us; speedup vs baseline: 1.0973x; 1.0973x over previous
//
#include <hip/hip_runtime.h>

// GraphTransformerLayer — MI355X
// r6=574 ... r20=258.4 r26=259.8 r27=251.4 r28=257.9 (tail dbuf REGRESSED:
// LDS 80KB -> 1 blk/CU -> 313 blocks ran in TWO rounds; 52.8 = 2 x 26us.
// Proof the dbuf cut t_block 44->26us — geometry ate it).
// r29: keep dbuf, fix geometry: tail = 320 thr (5 waves) x 80 rows -> 250
//      blocks = one block per CU, ONE round. Waves 0-3 stage (same 2048-elem
//      pattern), wave 4 compute-only. htile 20KB; LDS 86016 (1 blk/CU by
//      design). Math bit-identical to r28.
#define NN 20000
#define EE 160000
#define DD 128
#define GHC 512
#define INV_SQRT_HC 0.08838834764831845f  // 1/sqrt(128)

typedef __attribute__((ext_vector_type(8))) short short8;
typedef __attribute__((ext_vector_type(4))) short short4v;
typedef __attribute__((ext_vector_type(4))) float float4v;
typedef __attribute__((ext_vector_type(2))) float float2v;
typedef __attribute__((ext_vector_type(4))) unsigned uint4v;
typedef __attribute__((ext_vector_type(2))) unsigned uint2v;

__device__ inline float bf2f(unsigned short u) {
    union { unsigned u; float f; } x; x.u = ((unsigned)u) << 16; return x.f;
}
__device__ inline unsigned short f2bf(float f) {
    union { float f; unsigned u; } x; x.f = f;
    unsigned u = x.u;
    unsigned r = (u + 0x7fffu + ((u >> 16) & 1u)) >> 16;
    return (unsigned short)r;
}
// in-lane pair pack: D.lo = bf16(a), D.hi = bf16(b)  [gfx950; T12/m240 recipe]
__device__ inline unsigned cvt_pk_bf16(float a, float b) {
    unsigned d;
    asm("v_cvt_pk_bf16_f32 %0, %1, %2" : "=v"(d) : "v"(a), "v"(b));
    return d;
}

// async global->LDS 16B DMA: LDS dest must be WAVE-UNIFORM base (+lane*16 HW),
// global src is per-lane (m104/m97). Drained by the vmcnt(0) at __syncthreads.
__device__ inline void stage16(const short8* gsrc, short8* ldst) {
    __builtin_amdgcn_global_load_lds(
        (const __attribute__((address_space(1))) void*)gsrc,
        (__attribute__((address_space(3))) void*)ldst, 16, 0, 0);
}

// ---------------- fp8 e4m3 pack/unpack (HW cvt on gfx950; sw fallback) -----
#if defined(__has_builtin)
#if __has_builtin(__builtin_amdgcn_cvt_pk_f32_fp8) && __has_builtin(__builtin_amdgcn_cvt_pk_fp8_f32)
#define HW_FP8 1
#endif
#endif
#ifndef HW_FP8
#define HW_FP8 0
#endif

#if !HW_FP8
__device__ inline unsigned char sw_enc_fp8(float f) {
    if (!(f == f)) return 0x7f;
    unsigned s = (f < 0.f) ? 0x80u : 0u;
    float a = fabsf(f);
    if (a >= 448.f) return (unsigned char)(s | 0x7e);
    if (a < 5.96046448e-8f) return (unsigned char)s;
    int e; frexpf(a, &e);
    int E = e - 1;
    if (E < -6) E = -6;
    float q = ldexpf(rintf(ldexpf(a, 3 - E)), E - 3);
    if (q == 0.f) return (unsigned char)s;
    union { float f; unsigned u; } x; x.f = q;
    int qe = (int)((x.u >> 23) & 0xff) - 127;
    if (qe < -6) {
        unsigned mant = (unsigned)rintf(ldexpf(q, 9));
        return (unsigned char)(s | mant);
    }
    unsigned mant = (x.u >> 20) & 7;
    int ebits = qe + 7;
    if (ebits > 15) { ebits = 15; mant = 6; }
    return (unsigned char)(s | ((unsigned)ebits << 3) | mant);
}
__device__ inline float sw_dec_fp8(unsigned char u) {
    unsigned s = u >> 7, e = (u >> 3) & 15, m = u & 7;
    float v = e ? ldexpf((float)(8 + m), (int)e - 10) : ldexpf((float)m, -9);
    return s ? -v : v;
}
#endif

// pack 4 floats -> 4 fp8 bytes in one dword (word-sel imm per r14 lesson)
__device__ inline unsigned fp8_enc4(float a, float b, float c, float d) {
#if HW_FP8
    int r = __builtin_amdgcn_cvt_pk_fp8_f32(a, b, 0, false);
    r = __builtin_amdgcn_cvt_pk_fp8_f32(c, d, r, true);
    return (unsigned)r;
#else
    return (unsigned)sw_enc_fp8(a) | ((unsigned)sw_enc_fp8(b) << 8)
         | ((unsigned)sw_enc_fp8(c) << 16) | ((unsigned)sw_enc_fp8(d) << 24);
#endif
}
__device__ inline float2v fp8_dec2_lo(unsigned w) {
#if HW_FP8
    return __builtin_amdgcn_cvt_pk_f32_fp8((int)w, false);
#else
    float2v r;
    r[0] = sw_dec_fp8((unsigned char)(w & 0xff));
    r[1] = sw_dec_fp8((unsigned char)((w >> 8) & 0xff));
    return r;
#endif
}
__device__ inline float2v fp8_dec2_hi(unsigned w) {
#if HW_FP8
    return __builtin_amdgcn_cvt_pk_f32_fp8((int)w, true);
#else
    float2v r;
    r[0] = sw_dec_fp8((unsigned char)((w >> 16) & 0xff));
    r[1] = sw_dec_fp8((unsigned char)(w >> 24));
    return r;
#endif
}

// ---------------------------------------------------------------------------
// prep: [0,1024) convert x+te -> bf16 | [1024,1600) weight pack |
//       [1600,1664) wcomb | [1664,+EB) dst histogram.  One dispatch.
// ---------------------------------------------------------------------------
struct WPack { const void* in[18]; };
__device__ __constant__ const int WSZ[18] = {
    65536, 65536, 65536, 512, 512, 512,
    16384, 128, 65536, 512, 65536, 128,
    128, 128, 128, 128, 128, 128 };

__global__ void prep_kernel(const float* __restrict__ x, const float* __restrict__ te,
                            unsigned short* __restrict__ xcout, WPack p,
                            unsigned short* __restrict__ wcout,
                            const float* __restrict__ wv, const float* __restrict__ bv,
                            const float* __restrict__ wo, const float* __restrict__ bo,
                            unsigned short* __restrict__ wcomb,
                            unsigned short* __restrict__ bcomb,
                            const int* __restrict__ e_dst, int* __restrict__ counts)
{
    const int b = blockIdx.x;
    const int tid = threadIdx.x;
    if (b < 1024) {
        const long n4half = (long)NN * DD / 4;
        short4v* out4 = reinterpret_cast<short4v*>(xcout);
        long i = (long)b * 256 + tid;
        const long stride = 1024L * 256;
        const long tot = 2 * n4half;
        for (; i < tot; i += stride) {
            const float4v* src = (i < n4half)
                ? reinterpret_cast<const float4v*>(x)
                : reinterpret_cast<const float4v*>(te) - n4half;
            float4v v = src[i];
            short4v o;
            o[0] = (short)f2bf(v[0]); o[1] = (short)f2bf(v[1]);
            o[2] = (short)f2bf(v[2]); o[3] = (short)f2bf(v[3]);
            out4[i] = o;
        }
    } else if (b < 1600) {
        const int seg = (b - 1024) >> 5;
        const int rep = (b - 1024) & 31;
        int off = 0;
#pragma unroll
        for (int s = 0; s < 18; ++s) if (s < seg) off += WSZ[s];
        const int n = WSZ[seg];
        const float* q = (const float*)p.in[seg];
        for (int i = rep * 256 + tid; i < n; i += 32 * 256)
            wcout[off + i] = f2bf(q[i]);
    } else if (b < 1664) {
        int e = (b - 1600) * 256 + tid;   // 16384 total
        int i = e >> 7, kk = e & 127;
        float s = 0.f;
        for (int j = 0; j < 128; ++j)
            s += wo[i * 128 + j] * wv[j * 128 + kk];
        wcomb[e] = f2bf(s);
        if (b == 1600 && tid < 128) {
            float t = 0.f;
            for (int j = 0; j < 128; ++j) t += wo[tid * 128 + j] * bv[j];
            bcomb[tid] = f2bf(t + bo[tid]);
        }
    } else {
        int e = (b - 1664) * 256 + tid;
        if (e < EE) {
            int d = e_dst[e];
            if (d >= 0 && d < NN) atomicAdd(&counts[d], 1);
        }
    }
}

// ---------------------------------------------------------------------------
// GEMM v6 (r20, BEST): K=128, 128 cols/block, 256 rows/block = 4 row-tiles,
// SWAPPED operands mfma(W,x) -> lane holds row m=l&15, 4 consecutive cols.
// In-lane cvt_pk epilogues -> XOR-swizzled LDS -> b128 stores. W slab (32KB)
// staged once via global_load_lds DMA; LDS 40960 = 4 blk/CU. Bijective
// XCD-chunked 1D remap. cols < split -> bf16 out; >= split -> fp8 kv rows.
// ---------------------------------------------------------------------------
__global__ __launch_bounds__(256) void gemm3_kernel(
    const unsigned short* __restrict__ A, const unsigned short* __restrict__ W,
    const unsigned short* __restrict__ bias, unsigned short* __restrict__ out,
    unsigned char* __restrict__ kvout, int M, int Nout, int split, int relu,
    int nxg, int ncol)
{
    __shared__ short8 wslab[2048];                                       // 32 KB
    __shared__ __attribute__((aligned(16))) unsigned stile4[4][16][32];  //  8 KB
    const int tid  = threadIdx.x;
    const int lane = tid & 63;
    const int wid  = tid >> 6;
    const int quad = lane >> 4;
    const int l15  = lane & 15;

    // bijective XCD-chunked remap (m204)
    const int nb  = nxg * ncol;
    const int qq  = nb >> 3, rm = nb & 7;
    const int xcd = blockIdx.x & 7, slot = blockIdx.x >> 3;
    const int c   = (xcd < rm) ? xcd * (qq + 1) + slot
                               : rm * (qq + 1) + (xcd - rm) * qq + slot;
    const int xg = c / ncol;              // row-group (256 rows)
    const int yg = c - xg * ncol;         // col-slab
    const int colbase0 = yg * 128;
    const int rowg = xg * 256;

    const bool isfp8 = (colbase0 >= split);
    const int kvcol = colbase0 - split;              // 0..1023 when fp8
    const int which = isfp8 ? (kvcol >> 9) : 0;      // 0=k, 1=v
    const int head  = isfp8 ? ((kvcol & 511) >> 7) : 0;

    const short8* A8 = reinterpret_cast<const short8*>(A);
    const short8* W8 = reinterpret_cast<const short8*>(W);

    // tile-0 A loads issued first: latency hides under W staging
    short8 a4[4];
    {
        int arow = rowg + wid * 16 + l15;
        if (arow >= M) arow = M - 1;
#pragma unroll
        for (int i = 0; i < 4; ++i) a4[i] = A8[(size_t)arow * 16 + i * 4 + quad];
    }

    // W slab DMA: LDS element f = rep*256 + wid*64 + lane (wave-linear)
#pragma unroll
    for (int rep = 0; rep < 8; ++rep) {
        const int fi  = (rep * 4 + wid) & 3;
        const int ft  = rep & 3;
        const int ftt = rep >> 2;
        const int wrow = colbase0 + ftt * 64 + 16 * ft + l15;
        stage16(&W8[(size_t)wrow * 16 + fi * 4 + quad], &wslab[rep * 256 + wid * 64]);
    }

    // per-lane bias: 4 consecutive cols per (tt,t) at n0 = tt*64+16t+quad*4
    short4v bs4[2][4];
#pragma unroll
    for (int tt = 0; tt < 2; ++tt)
#pragma unroll
        for (int t = 0; t < 4; ++t)
            bs4[tt][t] = *reinterpret_cast<const short4v*>(
                &bias[colbase0 + tt * 64 + 16 * t + quad * 4]);

    __syncthreads();

    unsigned* fpd = &stile4[wid][0][0];   // dword view, per-wave 2 KB

#pragma unroll
    for (int tg = 0; tg < 4; ++tg) {
        const int rowbase = rowg + tg * 64 + wid * 16;

        // prefetch next tile's A under this tile's compute
        short8 a4n[4];
        if (tg < 3) {
            int arow = rowbase + 64 + l15;
            if (arow >= M) arow = M - 1;
#pragma unroll
            for (int i = 0; i < 4; ++i) a4n[i] = A8[(size_t)arow * 16 + i * 4 + quad];
        }

#pragma unroll
        for (int tt = 0; tt < 2; ++tt) {
            float4v acc[4];
#pragma unroll
            for (int t = 0; t < 4; ++t) acc[t] = (float4v){0.f, 0.f, 0.f, 0.f};

#pragma unroll
            for (int i = 0; i < 4; ++i) {
#pragma unroll
                for (int t = 0; t < 4; ++t) {
                    short8 wb = wslab[((tt * 4 + t) * 4 + i) * 64 + lane];
                    acc[t] = __builtin_amdgcn_mfma_f32_16x16x32_bf16(wb, a4[i], acc[t], 0, 0, 0);
                }
            }

            if (!isfp8) {
                // in-lane pack: 2 dwords (4 bf16 cols) per (t); XOR-swizzled LDS
#pragma unroll
                for (int t = 0; t < 4; ++t) {
                    float v0 = acc[t][0] + bf2f((unsigned short)bs4[tt][t][0]);
                    float v1 = acc[t][1] + bf2f((unsigned short)bs4[tt][t][1]);
                    float v2 = acc[t][2] + bf2f((unsigned short)bs4[tt][t][2]);
                    float v3 = acc[t][3] + bf2f((unsigned short)bs4[tt][t][3]);
                    if (relu) {
                        v0 = fmaxf(v0, 0.f); v1 = fmaxf(v1, 0.f);
                        v2 = fmaxf(v2, 0.f); v3 = fmaxf(v3, 0.f);
                    }
                    uint2v d = { cvt_pk_bf16(v0, v1), cvt_pk_bf16(v2, v3) };
                    const int dc = (8 * t + quad * 2) ^ ((l15 & 7) << 2);
                    *reinterpret_cast<uint2v*>(&stile4[wid][l15][dc]) = d;
                }
                const int rr0 = lane >> 3;
                const int cd  = (lane & 7) * 4;
#pragma unroll
                for (int it = 0; it < 2; ++it) {
                    int rw = rr0 + it * 8;
                    int grow = rowbase + rw;
                    if (grow < M) {
                        const int cs = cd ^ ((rw & 7) << 2);
                        uint4v v = *reinterpret_cast<const uint4v*>(&stile4[wid][rw][cs]);
                        *reinterpret_cast<uint4v*>(&out[(size_t)grow * Nout + colbase0 + tt * 64 + cd * 2]) = v;
                    }
                }
            } else {
                // fp8: in-lane 4-byte pack per (t); XOR-swizzled dword stage
#pragma unroll
                for (int t = 0; t < 4; ++t) {
                    float v0 = (acc[t][0] + bf2f((unsigned short)bs4[tt][t][0])) * 256.f;
                    float v1 = (acc[t][1] + bf2f((unsigned short)bs4[tt][t][1])) * 256.f;
                    float v2 = (acc[t][2] + bf2f((unsigned short)bs4[tt][t][2])) * 256.f;
                    float v3 = (acc[t][3] + bf2f((unsigned short)bs4[tt][t][3])) * 256.f;
                    const int dc = (tt * 16 + 4 * t + quad) ^ ((l15 & 7) << 2);
                    fpd[l15 * 32 + dc] = fp8_enc4(v0, v1, v2, v3);
                }
            }
        }

        if (isfp8) {
            // one store pass: 16 rows x 128B contiguous (full cache lines)
#pragma unroll
            for (int it = 0; it < 2; ++it) {
                int u = lane + it * 64;          // 0..127
                int row = u >> 3;                // 0..15
                int part = u & 7;                // 0..7 (16B each)
                int grow = rowbase + row;
                if (grow < M) {
                    const int db = row * 32 + ((part * 4) ^ ((row & 7) << 2));
                    uint4v v = *reinterpret_cast<const uint4v*>(&fpd[db]);
                    size_t ro = (size_t)grow * 1024 + (size_t)which * 512
                              + (size_t)head * 128 + (size_t)part * 16;
                    *reinterpret_cast<uint4v*>(kvout + ro) = v;
                }
            }
        }

        if (tg < 3) {
#pragma unroll
            for (int i = 0; i < 4; ++i) a4[i] = a4n[i];
        }
    }
}

// stage a 128-row W block: rows RO+wrow, row stride RS8 short8s, col off CO8
// (issued by waves 0-3 only; covers 2048 short8 elements)
#define STAGE_W(W8, RS8, CO8, RO, WS) do {                                    \
    _Pragma("unroll")                                                         \
    for (int rep_ = 0; rep_ < 8; ++rep_) {                                    \
        const int fi_  = (rep_ * 4 + wid) & 3;                                \
        const int ft_  = rep_ & 3;                                            \
        const int ftt_ = rep_ >> 2;                                           \
        const int wrow_ = (RO) + ftt_ * 64 + 16 * ft_ + l15;                  \
        stage16(&(W8)[(size_t)wrow_ * (RS8) + (CO8) + fi_ * 4 + quad],        \
                &(WS)[rep_ * 256 + wid * 64]);                                \
    } } while (0)

// acc[2][4] += ws(128x128) @ frags
#define MM128(WS, AF, ACC) do {                                               \
    _Pragma("unroll")                                                         \
    for (int tt_ = 0; tt_ < 2; ++tt_)                                         \
    _Pragma("unroll")                                                         \
    for (int i_ = 0; i_ < 4; ++i_)                                            \
    _Pragma("unroll")                                                         \
    for (int t_ = 0; t_ < 4; ++t_) {                                          \
        short8 wb_ = (WS)[((tt_ * 4 + t_) * 4 + i_) * 64 + lane];             \
        (ACC)[tt_][t_] = __builtin_amdgcn_mfma_f32_16x16x32_bf16(             \
            wb_, (AF)[i_], (ACC)[tt_][t_], 0, 0, 0);                          \
    } } while (0)

// ---------------------------------------------------------------------------
// TAIL (r29): r28 double-buffered schedule, 320 THREADS (5 waves) x 80 rows
// -> grid 250 = ONE block per CU, one round. Waves 0-3 stage W (same 2048-
// element pattern); wave 4 compute-only. htile 80x128 bf16 = 20KB.
// LDS = 2x32KB + 20KB = 86016 -> 1 blk/CU by design.
// ---------------------------------------------------------------------------
__global__ __launch_bounds__(320) void tail_kernel(
    const unsigned short* __restrict__ A1, const unsigned short* __restrict__ W1g,
    const unsigned short* __restrict__ b1g,
    const unsigned short* __restrict__ A2, const unsigned short* __restrict__ W2g,
    const unsigned short* __restrict__ b2g,
    const float* __restrict__ rx, const float* __restrict__ ragg,
    const unsigned short* __restrict__ g1, const unsigned short* __restrict__ be1,
    const unsigned short* __restrict__ g2, const unsigned short* __restrict__ be2,
    const unsigned short* __restrict__ fw1, const unsigned short* __restrict__ fb1,
    const unsigned short* __restrict__ fw2, const unsigned short* __restrict__ fb2,
    const unsigned short* __restrict__ g3, const unsigned short* __restrict__ be3,
    float* __restrict__ outf, int M)
{
    __shared__ short8 wsA[2048];                                          // 32 KB
    __shared__ short8 wsB[2048];                                          // 32 KB
    __shared__ __attribute__((aligned(16))) unsigned short htile[80 * 128]; // 20 KB
    const int tid  = threadIdx.x;
    const int lane = tid & 63;
    const int wid  = tid >> 6;            // 0..4
    const int quad = lane >> 4;
    const int l15  = lane & 15;
    const int rowbase = blockIdx.x * 80 + wid * 16;
    const int grow = rowbase + l15;
    const int gr = (grow < M) ? grow : M - 1;
    const int hrow = wid * 16 + l15;      // htile row (wave-private, 0..79)
    char* hb = reinterpret_cast<char*>(htile);
    const bool stager = (wid < 4);

    const short8* A81 = reinterpret_cast<const short8*>(A1);
    const short8* A82 = reinterpret_cast<const short8*>(A2);
    const short8* W81 = reinterpret_cast<const short8*>(W1g);
    const short8* W82 = reinterpret_cast<const short8*>(W2g);
    const short8* F18 = reinterpret_cast<const short8*>(fw1);  // 16 short8/row
    const short8* F28 = reinterpret_cast<const short8*>(fw2);  // 64 short8/row

    // ---- P0: stage gs_w->A AND wcomb->B; load both frag sets ----
    if (stager) {
        STAGE_W(W81, 16, 0, 0, wsA);
        STAGE_W(W82, 16, 0, 0, wsB);
    }
    short8 a4[4], a42[4];
#pragma unroll
    for (int i = 0; i < 4; ++i) {
        a4[i]  = A81[(size_t)gr * 16 + i * 4 + quad];
        a42[i] = A82[(size_t)gr * 16 + i * 4 + quad];
    }
    __syncthreads();   // A(gs_w) + B(wcomb) staged

    // ---- P1: MFMA1 from A ----
    float4v acc1[2][4];
#pragma unroll
    for (int tt = 0; tt < 2; ++tt)
#pragma unroll
        for (int t = 0; t < 4; ++t) acc1[tt][t] = (float4v){0.f, 0.f, 0.f, 0.f};
    MM128(wsA, a4, acc1);
    __syncthreads();   // all waves done reading A

    // issue F1 chunk0 -> A; its latency hides under LN1 + MFMA2
    if (stager) STAGE_W(F18, 16, 0, 0, wsA);

    // ---- LN1 in registers ----
    float x1[32];
    {
        float v[32];
#pragma unroll
        for (int tt = 0; tt < 2; ++tt)
#pragma unroll
            for (int t = 0; t < 4; ++t) {
                const int n0 = tt * 64 + 16 * t + quad * 4;
                short4v bs = *reinterpret_cast<const short4v*>(&b1g[n0]);
                float4v rv = *reinterpret_cast<const float4v*>(&rx[(size_t)gr * 128 + n0]);
                float4v cv = *reinterpret_cast<const float4v*>(&ragg[(size_t)gr * 128 + n0]);
#pragma unroll
                for (int r = 0; r < 4; ++r)
                    v[(tt * 4 + t) * 4 + r] = acc1[tt][t][r]
                        + bf2f((unsigned short)bs[r]) + rv[r] + cv[r];
            }
        float s = 0.f, sq = 0.f;
#pragma unroll
        for (int i = 0; i < 32; ++i) { s += v[i]; sq += v[i] * v[i]; }
        s  += __shfl_xor(s, 16, 64);  s  += __shfl_xor(s, 32, 64);
        sq += __shfl_xor(sq, 16, 64); sq += __shfl_xor(sq, 32, 64);
        float mu  = s * (1.f / 128.f);
        float var = sq * (1.f / 128.f) - mu * mu;
        float rs  = rsqrtf(fmaxf(var, 0.f) + 1e-5f);
#pragma unroll
        for (int tt = 0; tt < 2; ++tt)
#pragma unroll
            for (int t = 0; t < 4; ++t) {
                const int n0 = tt * 64 + 16 * t + quad * 4;
                short4v gg = *reinterpret_cast<const short4v*>(&g1[n0]);
                short4v bb = *reinterpret_cast<const short4v*>(&be1[n0]);
#pragma unroll
                for (int r = 0; r < 4; ++r)
                    x1[(tt * 4 + t) * 4 + r] = (v[(tt * 4 + t) * 4 + r] - mu) * rs
                        * bf2f((unsigned short)gg[r]) + bf2f((unsigned short)bb[r]);
            }
    }

    // ---- MFMA2 from B, LN2 -> x2 ----
    float4v acc2[2][4];
#pragma unroll
    for (int tt = 0; tt < 2; ++tt)
#pragma unroll
        for (int t = 0; t < 4; ++t) acc2[tt][t] = (float4v){0.f, 0.f, 0.f, 0.f};
    MM128(wsB, a42, acc2);

    float x2[32];
    {
        float v[32];
#pragma unroll
        for (int tt = 0; tt < 2; ++tt)
#pragma unroll
            for (int t = 0; t < 4; ++t) {
                const int n0 = tt * 64 + 16 * t + quad * 4;
                short4v bs = *reinterpret_cast<const short4v*>(&b2g[n0]);
#pragma unroll
                for (int r = 0; r < 4; ++r)
                    v[(tt * 4 + t) * 4 + r] = acc2[tt][t][r]
                        + bf2f((unsigned short)bs[r]) + x1[(tt * 4 + t) * 4 + r];
            }
        float s = 0.f, sq = 0.f;
#pragma unroll
        for (int i = 0; i < 32; ++i) { s += v[i]; sq += v[i] * v[i]; }
        s  += __shfl_xor(s, 16, 64);  s  += __shfl_xor(s, 32, 64);
        sq += __shfl_xor(sq, 16, 64); sq += __shfl_xor(sq, 32, 64);
        float mu  = s * (1.f / 128.f);
        float var = sq * (1.f / 128.f) - mu * mu;
        float rs  = rsqrtf(fmaxf(var, 0.f) + 1e-5f);
#pragma unroll
        for (int tt = 0; tt < 2; ++tt)
#pragma unroll
            for (int t = 0; t < 4; ++t) {
                const int n0 = tt * 64 + 16 * t + quad * 4;
                short4v gg = *reinterpret_cast<const short4v*>(&g2[n0]);
                short4v bb = *reinterpret_cast<const short4v*>(&be2[n0]);
#pragma unroll
                for (int r = 0; r < 4; ++r)
                    x2[(tt * 4 + t) * 4 + r] = (v[(tt * 4 + t) * 4 + r] - mu) * rs
                        * bf2f((unsigned short)gg[r]) + bf2f((unsigned short)bb[r]);
            }
    }

    // ---- x2 -> htile (wave-private rows, r21 swizzle); read A-fragments ----
#pragma unroll
    for (int tt = 0; tt < 2; ++tt)
#pragma unroll
        for (int t = 0; t < 4; ++t) {
            const int n0 = tt * 64 + 16 * t + quad * 4;
            const int idx = (tt * 4 + t) * 4;
            uint2v d = { cvt_pk_bf16(x2[idx], x2[idx + 1]),
                         cvt_pk_bf16(x2[idx + 2], x2[idx + 3]) };
            *reinterpret_cast<uint2v*>(
                hb + ((hrow * 256 + n0 * 2) ^ ((hrow & 7) << 4))) = d;
        }
    short8 af[4];
#pragma unroll
    for (int i = 0; i < 4; ++i)
        af[i] = *reinterpret_cast<const short8*>(
            hb + ((hrow * 256 + (i * 32 + quad * 8) * 2) ^ ((hrow & 7) << 4)));

    __syncthreads();   // A ready (F1c0); all waves done reading B

    // ---- FFN loop: A = F1[cc], B = F2[cc], double-buffered stages ----
    float4v accf[2][4];
#pragma unroll
    for (int tt = 0; tt < 2; ++tt)
#pragma unroll
        for (int t = 0; t < 4; ++t) accf[tt][t] = (float4v){0.f, 0.f, 0.f, 0.f};

    for (int cc = 0; cc < 4; ++cc) {
        // issue F2[cc] -> B; latency hides under up-gemm from A
        if (stager) STAGE_W(F28, 64, cc * 16, 0, wsB);

        // up-gemm: h = relu(x2 @ F1[cc] + b1), write own htile rows
        float4v au[2][4];
#pragma unroll
        for (int tt = 0; tt < 2; ++tt)
#pragma unroll
            for (int t = 0; t < 4; ++t) au[tt][t] = (float4v){0.f, 0.f, 0.f, 0.f};
        MM128(wsA, af, au);
#pragma unroll
        for (int tt = 0; tt < 2; ++tt)
#pragma unroll
            for (int t = 0; t < 4; ++t) {
                const int n0 = tt * 64 + 16 * t + quad * 4;
                short4v bs = *reinterpret_cast<const short4v*>(&fb1[cc * 128 + n0]);
                float v0 = fmaxf(au[tt][t][0] + bf2f((unsigned short)bs[0]), 0.f);
                float v1 = fmaxf(au[tt][t][1] + bf2f((unsigned short)bs[1]), 0.f);
                float v2 = fmaxf(au[tt][t][2] + bf2f((unsigned short)bs[2]), 0.f);
                float v3 = fmaxf(au[tt][t][3] + bf2f((unsigned short)bs[3]), 0.f);
                uint2v d = { cvt_pk_bf16(v0, v1), cvt_pk_bf16(v2, v3) };
                *reinterpret_cast<uint2v*>(
                    hb + ((hrow * 256 + n0 * 2) ^ ((hrow & 7) << 4))) = d;
            }
        __syncthreads();   // B ready (F2[cc]); all waves done reading A

        // issue F1[cc+1] -> A; latency hides under down-gemm from B
        if (stager && cc < 3) STAGE_W(F18, 16, 0, (cc + 1) * 128, wsA);

        // down-gemm: accf += h @ F2[cc]^T (h read from own htile rows)
        short8 h4[4];
#pragma unroll
        for (int i = 0; i < 4; ++i)
            h4[i] = *reinterpret_cast<const short8*>(
                hb + ((hrow * 256 + (i * 32 + quad * 8) * 2) ^ ((hrow & 7) << 4)));
        MM128(wsB, h4, accf);
        __syncthreads();   // A ready (F1[cc+1]); all waves done reading B
    }

    // ---- LN3 epilogue in regs (residual = x2 in regs) ----
    float v[32];
#pragma unroll
    for (int tt = 0; tt < 2; ++tt)
#pragma unroll
        for (int t = 0; t < 4; ++t) {
            const int n0 = tt * 64 + 16 * t + quad * 4;
            short4v bs = *reinterpret_cast<const short4v*>(&fb2[n0]);
#pragma unroll
            for (int r = 0; r < 4; ++r)
                v[(tt * 4 + t) * 4 + r] = accf[tt][t][r]
                    + bf2f((unsigned short)bs[r]) + x2[(tt * 4 + t) * 4 + r];
        }
    float s = 0.f, sq = 0.f;
#pragma unroll
    for (int i = 0; i < 32; ++i) { s += v[i]; sq += v[i] * v[i]; }
    s  += __shfl_xor(s, 16, 64);  s  += __shfl_xor(s, 32, 64);
    sq += __shfl_xor(sq, 16, 64); sq += __shfl_xor(sq, 32, 64);
    float mu  = s * (1.f / 128.f);
    float var = sq * (1.f / 128.f) - mu * mu;
    float rs  = rsqrtf(fmaxf(var, 0.f) + 1e-5f);

    if (grow < M) {
#pragma unroll
        for (int tt = 0; tt < 2; ++tt)
#pragma unroll
            for (int t = 0; t < 4; ++t) {
                const int n0 = tt * 64 + 16 * t + quad * 4;
                short4v gg = *reinterpret_cast<const short4v*>(&g3[n0]);
                short4v bb = *reinterpret_cast<const short4v*>(&be3[n0]);
                float4v ov;
#pragma unroll
                for (int r = 0; r < 4; ++r)
                    ov[r] = (v[(tt * 4 + t) * 4 + r] - mu) * rs
                            * bf2f((unsigned short)gg[r]) + bf2f((unsigned short)bb[r]);
                *reinterpret_cast<float4v*>(&outf[(size_t)grow * 128 + n0]) = ov;
            }
    }
}

// ---------------------------------------------------------------------------
// CSR scan + scatter (r20 proven versions)
// ---------------------------------------------------------------------------
__global__ __launch_bounds__(1024) void scan_kernel(
    const int* __restrict__ counts, int* __restrict__ offsets, int* __restrict__ pos, int n)
{
    __shared__ int wsum[16];
    __shared__ int carry_s;
    const int tid = threadIdx.x;
    const int wid = tid >> 6, lane = tid & 63;
    int vals[20];
#pragma unroll
    for (int cI = 0; cI < 20; ++cI) {
        int i = cI * 1024 + tid;
        vals[cI] = (i < n) ? counts[i] : 0;
    }
    if (tid == 0) carry_s = 0;
    __syncthreads();
#pragma unroll
    for (int cI = 0; cI < 20; ++cI) {
        int i = cI * 1024 + tid;
        int val = vals[cI];
        int x = val;
#pragma unroll
        for (int off = 1; off < 64; off <<= 1) {
            int t = __shfl_up(x, off, 64);
            if (lane >= off) x += t;
        }
        if (lane == 63) wsum[wid] = x;
        __syncthreads();
        if (wid == 0 && lane < 16) {
            int s = wsum[lane];
#pragma unroll
            for (int off = 1; off < 16; off <<= 1) {
                int t = __shfl_up(s, off, 64);
                if (lane >= off) s += t;
            }
            wsum[lane] = s;
        }
        __syncthreads();
        int prefix = (wid > 0 ? wsum[wid - 1] : 0) + carry_s;
        int ex = prefix + x - val;
        if (i < n) { offsets[i] = ex; pos[i] = ex; }
        __syncthreads();
        if (tid == 0) carry_s += wsum[15];
        __syncthreads();
    }
    if (tid == 0) offsets[n] = carry_s;
}

__global__ void scatter_kernel(const int* __restrict__ src, const int* __restrict__ dst,
                               int* __restrict__ pos, int* __restrict__ sorted_src, int E)
{
    int e = blockIdx.x * 256 + threadIdx.x;
    if (e < E) {
        int d = dst[e];
        if (d >= 0 && d < NN) {
            int p = atomicAdd(&pos[d], 1);
            if (p >= 0 && p < E) sorted_src[p] = src[e];
        }
    }
}

// ---------------------------------------------------------------------------
// All-heads graph attention over fp8 kv (r26): 2 waves/node, 4-deep load
// groups, sacc padded [..][9] (conflict-free publish, measured r25 2.88M).
// ---------------------------------------------------------------------------
__device__ inline void agg_edge(const uint2v& kk, const uint2v& vv,
                                const float* qf, float* acc, float& ssum)
{
    float2v k01 = fp8_dec2_lo(kk[0]);
    float2v k23 = fp8_dec2_hi(kk[0]);
    float2v k45 = fp8_dec2_lo(kk[1]);
    float2v k67 = fp8_dec2_hi(kk[1]);
    float dot = qf[0] * k01[0] + qf[1] * k01[1] + qf[2] * k23[0] + qf[3] * k23[1]
              + qf[4] * k45[0] + qf[5] * k45[1] + qf[6] * k67[0] + qf[7] * k67[1];
    dot += __shfl_xor(dot, 1, 64);
    dot += __shfl_xor(dot, 2, 64);
    dot += __shfl_xor(dot, 4, 64);
    dot += __shfl_xor(dot, 8, 64);
    float pp = __expf(dot);
    ssum += pp;
    float2v v01 = fp8_dec2_lo(vv[0]);
    float2v v23 = fp8_dec2_hi(vv[0]);
    float2v v45 = fp8_dec2_lo(vv[1]);
    float2v v67 = fp8_dec2_hi(vv[1]);
    acc[0] += pp * v01[0]; acc[1] += pp * v01[1];
    acc[2] += pp * v23[0]; acc[3] += pp * v23[1];
    acc[4] += pp * v45[0]; acc[5] += pp * v45[1];
    acc[6] += pp * v67[0]; acc[7] += pp * v67[1];
}

__global__ __launch_bounds__(256) void agg_kernel(
    const unsigned short* __restrict__ q, const unsigned char* __restrict__ kvb,
    const int* __restrict__ offsets, const int* __restrict__ srcs,
    float* __restrict__ aggb)
{
    __shared__ float sacc[4][64][9];     // padded: conflict-free publish
    __shared__ float sssum[4][64];
    const int tid  = threadIdx.x;
    const int wid  = tid >> 6;
    const int lane = tid & 63;
    const int node = blockIdx.x * 2 + (wid >> 1);
    const int half = wid & 1;

    const short8* q8 = reinterpret_cast<const short8*>(q);
    const int fidx = (lane >> 4) * 16 + (lane & 15);
    const int koff = fidx * 8;            // head*128 + sub*8

    short8 qv = q8[(size_t)node * 64 + fidx];
    float qf[8];
#pragma unroll
    for (int i = 0; i < 8; ++i)
        qf[i] = bf2f((unsigned short)qv[i]) * (INV_SQRT_HC / 256.f);

    int beg = offsets[node], end = offsets[node + 1];
    if (beg < 0) beg = 0;
    if (end > EE) end = EE;
    float ssum = 0.f;
    float acc[8];
#pragma unroll
    for (int i = 0; i < 8; ++i) acc[i] = 0.f;

    const int start = beg + half;
    int nce = (end > start) ? ((end - start + 1) >> 1) : 0;
    int ncap = (nce > 64) ? 64 : nce;

    int sv = 0;
    if (lane < ncap) {
        int s = srcs[start + 2 * lane];
        if (s < 0) s = 0;
        if (s >= NN) s = NN - 1;
        sv = s;
    }
    // groups of 4: issue all loads, then compute (4 outstanding L3 reqs)
    for (int base = 0; base < ncap; base += 4) {
        const int rem = ncap - base;
        uint2v k0{}, v0{}, k1{}, v1{}, k2{}, v2{}, k3{}, v3{};
        {
            int s = __shfl(sv, base, 64);
            const unsigned char* p = kvb + (size_t)s * 1024 + koff;
            k0 = *reinterpret_cast<const uint2v*>(p);
            v0 = *reinterpret_cast<const uint2v*>(p + 512);
        }
        if (rem > 1) {
            int s = __shfl(sv, base + 1, 64);
            const unsigned char* p = kvb + (size_t)s * 1024 + koff;
            k1 = *reinterpret_cast<const uint2v*>(p);
            v1 = *reinterpret_cast<const uint2v*>(p + 512);
        }
        if (rem > 2) {
            int s = __shfl(sv, base + 2, 64);
            const unsigned char* p = kvb + (size_t)s * 1024 + koff;
            k2 = *reinterpret_cast<const uint2v*>(p);
            v2 = *reinterpret_cast<const uint2v*>(p + 512);
        }
        if (rem > 3) {
            int s = __shfl(sv, base + 3, 64);
            const unsigned char* p = kvb + (size_t)s * 1024 + koff;
            k3 = *reinterpret_cast<const uint2v*>(p);
            v3 = *reinterpret_cast<const uint2v*>(p + 512);
        }
        agg_edge(k0, v0, qf, acc, ssum);
        if (rem > 1) agg_edge(k1, v1, qf, acc, ssum);
        if (rem > 2) agg_edge(k2, v2, qf, acc, ssum);
        if (rem > 3) agg_edge(k3, v3, qf, acc, ssum);
    }
    for (int j = start + 128; j < end; j += 2) {   // pathological-degree tail
        int s = srcs[j];
        if (s < 0) s = 0;
        if (s >= NN) s = NN - 1;
        uint2v kc = *reinterpret_cast<const uint2v*>(kvb + (size_t)s * 1024 + koff);
        uint2v vc = *reinterpret_cast<const uint2v*>(kvb + (size_t)s * 1024 + 512 + koff);
        agg_edge(kc, vc, qf, acc, ssum);
    }

    // publish partials; even wave combines
#pragma unroll
    for (int i = 0; i < 8; ++i) sacc[wid][lane][i] = acc[i];
    sssum[wid][lane] = ssum;
    __syncthreads();
    if (half == 0) {
#pragma unroll
        for (int i = 0; i < 8; ++i) acc[i] += sacc[wid ^ 1][lane][i];
        ssum += sssum[wid ^ 1][lane];

        float inv = (ssum > 0.f) ? 1.f / (256.f * ssum) : 0.f;   // undo x256
#pragma unroll
        for (int i = 0; i < 8; ++i) acc[i] *= inv;
#pragma unroll
        for (int i = 0; i < 8; ++i) {
            acc[i] += __shfl_xor(acc[i], 16, 64);
            acc[i] += __shfl_xor(acc[i], 32, 64);
            acc[i] *= 0.25f;
        }
        if (lane < 16) {
            float4v* o = reinterpret_cast<float4v*>(aggb + (size_t)node * 128 + lane * 8);
            o[0] = (float4v){acc[0], acc[1], acc[2], acc[3]};
            o[1] = (float4v){acc[4], acc[5], acc[6], acc[7]};
        }
    }
}

// ---------------------------------------------------------------------------
extern "C" void kernel_launch(void* const* d_in, const int* in_sizes, int n_in,
                              void* d_out, int out_size, void* d_ws, size_t ws_size,
                              hipStream_t stream)
{
    const int* edge_index = (const int*)d_in[28];
    const int* e_src = edge_index;
    const int* e_dst = edge_index + EE;

    if (n_in < 29 || in_sizes[0] != NN * DD || in_sizes[28] != 2 * EE || out_size != NN * DD)
        return;

    const size_t SZ_OFF  = (size_t)(NN + 16) * 4;
    const size_t SZ_CNT  = (size_t)NN * 4;
    const size_t SZ_SS   = (size_t)EE * 4;
    const size_t SZ_SM   = (size_t)NN * DD * 2;     //  5.12 MB
    const size_t SZ_F32  = (size_t)NN * DD * 4;     // 10.24 MB
    const size_t SZ_Q    = (size_t)NN * 512 * 2;    // 20.48 MB
    const size_t SZ_KV   = (size_t)NN * 1024;       // 20.48 MB (fp8)
    const size_t SZ_HB   = (size_t)NN * GHC * 2;    // 20.48 MB (unused, kept)
    const size_t WC_ELE  = 347136;
    const size_t SZ_WC   = WC_ELE * 2;
    const size_t SZ_WCB  = 16384 * 2 + 256;
    const size_t REQUIRED = SZ_OFF + 2 * SZ_CNT + SZ_SS + 2 * SZ_SM + SZ_WC + SZ_WCB
                          + SZ_Q + SZ_KV + 3 * SZ_F32 + SZ_SM + SZ_HB;

    if (ws_size < REQUIRED) return;

    char* w = (char*)d_ws;
    int* offsets = (int*)w;        w += SZ_OFF;
    int* counts  = (int*)w;        w += SZ_CNT;
    int* pos     = (int*)w;        w += SZ_CNT;
    int* sorted_src = (int*)w;     w += SZ_SS;
    unsigned short* xc   = (unsigned short*)w; w += SZ_SM;
    unsigned short* tec  = (unsigned short*)w; w += SZ_SM;
    unsigned short* wc   = (unsigned short*)w; w += SZ_WC;
    unsigned short* wcomb = (unsigned short*)w; w += 16384 * 2;
    unsigned short* bcomb = (unsigned short*)w; w += 256;
    unsigned short* qb   = (unsigned short*)w; w += SZ_Q;
    unsigned char*  kvb  = (unsigned char*)w;  w += SZ_KV;
    float*          aggb = (float*)w;          w += SZ_F32;
    float*          x1f  = (float*)w;          w += SZ_F32;   // unused (kept layout)
    float*          x2f  = (float*)w;          w += SZ_F32;   // unused (kept layout)
    unsigned short* x2b  = (unsigned short*)w; w += SZ_SM;    // unused (kept layout)
    unsigned short* hbuf = (unsigned short*)w; w += SZ_HB;    // unused (kept layout)
    (void)x1f; (void)x2f; (void)x2b; (void)hbuf;

    unsigned short* cw = wc;
    unsigned short* qkv_w = cw; cw += 3 * 65536;
    unsigned short* qkv_b = cw; cw += 3 * 512;
    unsigned short* gs_w  = cw; cw += 16384;  unsigned short* gs_b  = cw; cw += 128;
    unsigned short* ffn_w1 = cw; cw += 65536; unsigned short* ffn_b1 = cw; cw += 512;
    unsigned short* ffn_w2 = cw; cw += 65536; unsigned short* ffn_b2 = cw; cw += 128;
    unsigned short* ln1_g = cw; cw += 128;    unsigned short* ln1_b = cw; cw += 128;
    unsigned short* ln2_g = cw; cw += 128;    unsigned short* ln2_b = cw; cw += 128;
    unsigned short* ln3_g = cw; cw += 128;    unsigned short* ln3_b = cw; cw += 128;

    const int EB = (EE + 255) / 256;
    const dim3 blk(256);
    const int MB2 = (NN + 255) / 256;         // 79
    const int TB = (NN + 79) / 80;            // 250 tail blocks (80 rows each)

    WPack pack;
    const int live_idx[18] = {2,4,6, 3,5,7, 8,9, 18,19, 20,21, 22,23,24,25,26,27};
    for (int i = 0; i < 18; ++i) pack.in[i] = d_in[live_idx[i]];

    (void)hipMemsetAsync(counts, 0, SZ_CNT, stream);
    prep_kernel<<<1664 + EB, blk, 0, stream>>>((const float*)d_in[0], (const float*)d_in[1],
                                               xc, pack, wc,
                                               (const float*)d_in[14], (const float*)d_in[15],
                                               (const float*)d_in[16], (const float*)d_in[17],
                                               wcomb, bcomb, e_dst, counts);

    scan_kernel<<<1, 1024, 0, stream>>>(counts, offsets, pos, NN);
    scatter_kernel<<<EB, blk, 0, stream>>>(e_src, e_dst, pos, sorted_src, EE);

    // TransformerConv: QKV (q bf16 -> qb; k|v fp8 -> kvb), agg
    gemm3_kernel<<<dim3(MB2 * 12), blk, 0, stream>>>(xc, qkv_w, qkv_b, qb, kvb,
                                                     NN, 512, 512, 0, MB2, 12);
    agg_kernel<<<NN / 2, blk, 0, stream>>>(qb, kvb, offsets, sorted_src, aggb);

    // TAIL: ln12 + FFN + LN3 fused (row-local, dbuf W, 250 blocks x 320 thr)
    tail_kernel<<<TB, dim3(320), 0, stream>>>(xc, gs_w, gs_b,
                                              tec, wcomb, bcomb,
                                              (const float*)d_in[0], aggb,
                                              ln1_g, ln1_b, ln2_g, ln2_b,
                                              ffn_w1, ffn_b1, ffn_w2, ffn_b2,
                                              ln3_g, ln3_b, (float*)d_out, NN);
}